// Round 7
// baseline (266.397 us; speedup 1.0000x reference)
//
#include <hip/hip_runtime.h>
#include <hip/hip_bf16.h>

// SegmentDeactivation: KAN layer folded into one bf16 GEMM.
// K = 512*36 (dense-ified 4-sparse cubic B-spline bases) + 512 (silu(x)·W_base)
//   + 512 (x·masked-slope) = 19456. bias = sum of masked intercepts.
// R17: MEASUREMENT ROUND. Source identical to R15 (best, 136.2us); the only
//      change is gemm_fused launched 5x (idempotent: A,B -> P bit-identical
//      each replay). gemm_steady = (dur_us - 136.2)/4. Pre-committed rule:
//      g >= 30 -> port 8-phase counted-vmcnt 256^2 schedule next;
//      g <= 22 -> gemm is minor, attack prep/overhead next.
//      R16's BK=32 dbuf (+6us regression) reverted.

typedef unsigned short u16;
typedef unsigned int u32;
typedef unsigned long long u64;
typedef __attribute__((ext_vector_type(8))) short short8;
typedef __attribute__((ext_vector_type(4))) float floatx4;

#define IN_F 512
#define OUT_F 512
#define BATCH 1024
#define K_SPLINE (IN_F * 36)            // 18432
#define K_BASE_OFF K_SPLINE
#define K_LIN_OFF (K_SPLINE + IN_F)
#define K_TOT (K_SPLINE + 2 * IN_F)     // 19456
#define SPLITS 32                       // 16 x (10*64) + 16 x (9*64)
#define MN (BATCH * OUT_F)

static __device__ inline u16 f2b(float f) {
  union { float f; u32 u; } v; v.f = f;
  u32 r = v.u + 0x7FFFu + ((v.u >> 16) & 1u);  // round-nearest-even
  return (u16)(r >> 16);
}
static __device__ inline float b2f(u32 lo16) {  // bf16 bits (low 16) -> float
  union { u32 u; float f; } v; v.u = lo16 << 16; return v.f;
}

// ---- prep (fused): blocks 0..1023 = pack_b (one o-half each, per-block mask
//      detect, bias block-reduce); blocks 1024..3071 = dense-A build
//      (bix = blk-1024 = b*2 + half; thread t owns (b, i = i0+t)).
__global__ __launch_bounds__(256) void prep_kernel(
    const float* __restrict__ bw, const float* __restrict__ sw,
    const float* __restrict__ sc, const void* __restrict__ maskp,
    const float* __restrict__ x, u16* __restrict__ B,
    float* __restrict__ bias_part, u16* __restrict__ A) {
  __shared__ __align__(16) u64 lds64[1120 * 4];  // 35840B
  __shared__ int sflag;
  __shared__ float ws4[4];
  int blk = blockIdx.x, t = threadIdx.x;

  if (blk >= 1024) {
    // ---- dense A build
    int bix = blk - 1024;
    int b = bix >> 1;
    int i0 = (bix & 1) << 8;
    int i = i0 + t;
    float xv = x[(size_t)b * IN_F + i];

    // zero own 36-col row (72B = 9 u64), no barrier needed before scatter
    u64* myrow = lds64 + t * 9;
#pragma unroll
    for (int j = 0; j < 9; ++j) myrow[j] = 0;

    int mc = (int)floorf((xv + 1.1875f) * 16.0f);
    float gm = (float)mc * 0.0625f - 1.1875f;
    if (xv < gm) { mc -= 1; gm -= 0.0625f; }
    else if (xv >= gm + 0.0625f) { mc += 1; gm += 0.0625f; }
    if (mc >= 0 && mc <= 37) {
      float t_ = (xv - gm) * 16.0f;
      float t2 = t_ * t_, t3 = t2 * t_;
      float omt = 1.0f - t_;
      u16 r0 = f2b(omt * omt * omt * (1.0f / 6.0f));
      u16 r1 = f2b((3.0f * t3 - 6.0f * t2 + 4.0f) * (1.0f / 6.0f));
      u16 r2 = f2b((-3.0f * t3 + 3.0f * t2 + 3.0f * t_ + 1.0f) * (1.0f / 6.0f));
      float f0 = b2f(r0), f1 = b2f(r1), f2 = b2f(r2);
      u16 bv[4] = {r0, r1, r2, f2b(1.0f - f0 - f1 - f2)};
      u16* lds_u = (u16*)lds64;
#pragma unroll
      for (int j = 0; j < 4; ++j) {
        int c = mc - 3 + j;
        if ((u32)c < 35u) lds_u[t * 36 + c] = bv[j];
      }
    }
    __syncthreads();

    // coalesced dump: 256 rows x 36 u16 = 2304 u64
    u64* dstA = (u64*)(A + (size_t)b * K_TOT + (size_t)i0 * 36);
#pragma unroll
    for (int j = 0; j < 9; ++j) dstA[j * 256 + t] = lds64[j * 256 + t];

    // base / linear columns of A
    float sl = xv / (1.0f + __expf(-xv));
    A[(size_t)b * K_TOT + K_BASE_OFF + i] = f2b(sl);
    A[(size_t)b * K_TOT + K_LIN_OFF + i] = f2b(xv);
    return;
  }

  // ---- pack_b: id = o*512+i, o = blk>>1
  float* lds_f = (float*)lds64;
  int id = blk * 256 + t;
  int o = id >> 9, i = id & 511;
  int i0 = (blk & 1) * 256;

  // stage 35*256 floats = 2240 float4, vectorized (G13)
  const float* swb = sw + ((size_t)o * 512 + i0) * 35;
  const floatx4* sw4 = (const floatx4*)swb;
  floatx4* lds4 = (floatx4*)lds_f;
#pragma unroll
  for (int j = 0; j < 8; ++j) lds4[j * 256 + t] = sw4[j * 256 + t];
  if (t < 192) lds4[8 * 256 + t] = sw4[8 * 256 + t];

  // per-block mask dtype detect over THIS block's entries only.
  const u32* mw = (const u32*)maskp;
  if (t == 0) sflag = 0;
  __syncthreads();
  if (t < 64) {
    u32 w2 = mw[blk * 64 + t];   // uint8 window: bytes [blk*256,+256)
    if ((w2 & 0xFFFFFF00u) && w2 != 0x3F800000u) atomicOr(&sflag, 1);
  }
  __syncthreads();
  int fl = sflag;
  if (!(fl & 1)) {
    u32 w1 = mw[blk * 256 + t];  // int32/f32 window: words [blk*256,+256)
    if (w1 == 0x3F800000u) atomicOr(&sflag, 2);
  }
  __syncthreads();
  fl = sflag;
  bool mk;
  if (fl & 1)      mk = ((const unsigned char*)maskp)[id] != 0;
  else if (fl & 2) mk = ((const float*)maskp)[id] != 0.0f;
  else             mk = ((const int*)maskp)[id] != 0;

  float s = sc[id];
  float w[35];
#pragma unroll
  for (int c = 0; c < 35; ++c) w[c] = lds_f[t * 35 + c] * s;
  __syncthreads();

  // linear fallback params from endpoint spline values (dx = 2 exactly)
  float ys = (w[0] + 4.0f * w[1] + w[2]) * (1.0f / 6.0f);
  float ye = (w[32] + 4.0f * w[33] + w[34]) * (1.0f / 6.0f);
  float a = (ye - ys) * 0.5f;
  float bl = ys + a;

  // build out-row in regs (static indexing), store as 9 u64
  union { u16 r16[36]; u64 r64[9]; } ur;
#pragma unroll
  for (int c = 0; c < 35; ++c) ur.r16[c] = f2b(mk ? 0.0f : w[c]);
  ur.r16[35] = 0;
  u64* myrow = lds64 + t * 9;
#pragma unroll
  for (int j = 0; j < 9; ++j) myrow[j] = ur.r64[j];

  B[(size_t)o * K_TOT + K_BASE_OFF + i] = f2b(bw[id]);
  B[(size_t)o * K_TOT + K_LIN_OFF + i] = f2b(mk ? a : 0.0f);

  // bias block-reduce: sum of (mk ? bl : 0) over this block's 256 i's
  float v = mk ? bl : 0.0f;
#pragma unroll
  for (int off = 32; off >= 1; off >>= 1) v += __shfl_down(v, off);
  if ((t & 63) == 0) ws4[t >> 6] = v;
  __syncthreads();
  if (t == 0) bias_part[blk] = ws4[0] + ws4[1] + ws4[2] + ws4[3];

  u64* dst = (u64*)(B + (size_t)o * K_TOT + (size_t)i0 * 36);
#pragma unroll
  for (int j = 0; j < 9; ++j) dst[j * 256 + t] = lds64[j * 256 + t];
}

// ---- pure GEMM: 256x128 tile, BK=64, 16x16x32 bf16 MFMA, 512 threads
// (8 waves = 4M x 2N, each wave a 64x64 sub-tile, acc 4x4). Grid 512 =
// 2 blocks/CU, 16 waves/CU. Per epoch 6x global_load_lds width-16 per thread
// (4 A-groups + 2 B-groups; pre-swizzled global source -> linear LDS dest,
// XOR-swizzled read), sync, 32 MFMA/wave, sync.
// XCD chunking: p&7 = xcd -> (bn = xcd&3, ks parity = xcd>>2) fixed per XCD.
__global__ __launch_bounds__(512, 4) void gemm_fused(const u16* __restrict__ A,
                                                     const u16* __restrict__ Bp,
                                                     u16* __restrict__ P) {
  __shared__ u16 As[256 * 64];   // 32 KB
  __shared__ u16 Bs[128 * 64];   // 16 KB

  int t = threadIdx.x;
  int p = blockIdx.x;
  // bijective remap: xcd = p&7 hosts (bn = xcd&3, ks parity = xcd>>2)
  int x_ = p & 7, j = p >> 3;            // j 0..63
  int bm = j & 3, idx = j >> 2;          // bm 0..3, idx 0..15
  int bn = x_ & 3;
  int ks = 2 * idx + (x_ >> 2);          // 0..31
  int tile = (bm << 2) | bn;             // 0..15

  int w = t >> 6, l = t & 63;
  int wm = w & 3, wn = w >> 2;           // 4 M-waves x 2 N-waves

  floatx4 acc[4][4];
#pragma unroll
  for (int pp = 0; pp < 4; ++pp)
#pragma unroll
    for (int q = 0; q < 4; ++q) acc[pp][q] = (floatx4)0.0f;

  int nit = (ks < 16) ? 10 : 9;
  int k0s = (ks < 16) ? ks * 640 : 10240 + (ks - 16) * 576;

  // staging: thread t covers (row ra = t>>3 in each 64-row group, chunk t&7);
  // global source column pre-swizzled so linear LDS dest == swizzled layout.
  int ra = t >> 3;                       // 0..63
  int cg = (t & 7) ^ (ra & 7);
  const u16* Agp = A + (size_t)(bm * 256 + ra) * K_TOT + k0s + cg * 8;
  const u16* Bgp = Bp + (size_t)(bn * 128 + ra) * K_TOT + k0s + cg * 8;
  u16* Asp = As + t * 8;
  u16* Bsp = Bs + t * 8;

  int mr = l & 15;
  int cq = l >> 4;

  for (int kk = 0; kk < nit; ++kk) {
#pragma unroll
    for (int q = 0; q < 4; ++q)
      __builtin_amdgcn_global_load_lds(
          (const __attribute__((address_space(1))) void*)(Agp + (size_t)q * 64 * K_TOT),
          (__attribute__((address_space(3))) void*)(Asp + q * 4096), 16, 0, 0);
#pragma unroll
    for (int q = 0; q < 2; ++q)
      __builtin_amdgcn_global_load_lds(
          (const __attribute__((address_space(1))) void*)(Bgp + (size_t)q * 64 * K_TOT),
          (__attribute__((address_space(3))) void*)(Bsp + q * 4096), 16, 0, 0);
    Agp += 64;
    Bgp += 64;
    __syncthreads();   // implicit vmcnt drain: tiles landed

    // MFMA phase: wave (wm, wn) computes rows wm*64..+64 x cols wn*64..+64
#pragma unroll
    for (int h = 0; h < 2; ++h) {
      short8 af[4], bf[4];
      int c = h * 4 + cq;
#pragma unroll
      for (int tm = 0; tm < 4; ++tm) {
        int row = wm * 64 + tm * 16 + mr;
        af[tm] = *(const short8*)&As[row * 64 + ((c ^ (row & 7)) << 3)];
      }
#pragma unroll
      for (int tn = 0; tn < 4; ++tn) {
        int row = wn * 64 + tn * 16 + mr;
        bf[tn] = *(const short8*)&Bs[row * 64 + ((c ^ (row & 7)) << 3)];
      }
#pragma unroll
      for (int tm = 0; tm < 4; ++tm)
#pragma unroll
        for (int tn = 0; tn < 4; ++tn)
          acc[tm][tn] = __builtin_amdgcn_mfma_f32_16x16x32_bf16(af[tm], bf[tn], acc[tm][tn], 0, 0, 0);
    }
    __syncthreads();   // MFMA reads done before next iter overwrites
  }

  // ---- epilogue: direct coalesced bf16 partial store, fixed per-thread layout.
  // per (tile, ks): 256x128 = 32768 u16; chunk q (0..7) x 512 thr x 8 u16.
  u16* Pb = P + ((size_t)tile * SPLITS + ks) * 32768;
#pragma unroll
  for (int q = 0; q < 8; ++q) {
    int tm = q >> 1, tn0 = (q & 1) * 2;
    u16 r[8];
#pragma unroll
    for (int z = 0; z < 4; ++z) r[z] = f2b(acc[tm][tn0][z]);
#pragma unroll
    for (int z = 0; z < 4; ++z) r[4 + z] = f2b(acc[tm][tn0 + 1][z]);
    *(short8*)(Pb + q * 4096 + t * 8) = *(short8*)r;
  }
}

// ---- reduce 32 bf16 partial tiles + bias -> fp32 out (decodes C-layout)
__global__ __launch_bounds__(256) void reduce_kernel(const u16* __restrict__ P,
                                                     const float* __restrict__ bias_part,
                                                     float* __restrict__ out) {
  int rid = blockIdx.x * 256 + threadIdx.x;  // 65536 = tile*4096 + q*512 + t
  int tile = rid >> 12;                      // 0..15
  int rem = rid & 4095;
  int q = rem >> 9, t = rem & 511;
  const u16* base = P + (size_t)tile * SPLITS * 32768 + q * 4096 + t * 8;

  float s[8] = {0, 0, 0, 0, 0, 0, 0, 0};
#pragma unroll
  for (int ks = 0; ks < SPLITS; ++ks) {
    short8 v = *(const short8*)(base + (size_t)ks * 32768);
#pragma unroll
    for (int j = 0; j < 8; ++j) s[j] += b2f((u32)(u16)v[j]);
  }

  int w = t >> 6, l = t & 63;
  int wm = w & 3, wn = w >> 2;
  int bm = tile >> 2, bn = tile & 3;
  int row0 = bm * 256 + wm * 64 + ((l >> 4) << 2);
  int col0 = bn * 128 + wn * 64 + (l & 15);
  int tm = q >> 1, tn0 = (q & 1) * 2;
#pragma unroll
  for (int j = 0; j < 8; ++j) {
    int tn = tn0 + (j >> 2), rr = j & 3;
    int row = row0 + tm * 16 + rr;
    int col = col0 + tn * 16;
    float bsv = bias_part[2 * col] + bias_part[2 * col + 1];
    out[(size_t)row * OUT_F + col] = s[j] + bsv;
  }
}

extern "C" void kernel_launch(void* const* d_in, const int* in_sizes, int n_in,
                              void* d_out, int out_size, void* d_ws, size_t ws_size,
                              hipStream_t stream) {
  const float* x  = (const float*)d_in[0];
  const float* bw = (const float*)d_in[1];
  const float* sw = (const float*)d_in[2];
  const float* sc = (const float*)d_in[3];
  // d_in[4] = grid: uniform h=1/16 extended knots, constants baked in.
  const void* mask = d_in[5];

  const size_t B_BYTES = (size_t)OUT_F * K_TOT * 2;         // 19,922,944
  const size_t BIAS_OFF = B_BYTES;                          // 1024 floats
  const size_t A_OFF = B_BYTES + 8192;
  const size_t A_BYTES = (size_t)BATCH * K_TOT * 2;         // 39,845,888
  const size_t P_OFF = A_OFF + A_BYTES;                     // P: 33,554,432

  char* wsb = (char*)d_ws;
  u16* Bpack = (u16*)wsb;
  float* bias_part = (float*)(wsb + BIAS_OFF);
  u16* Adense = (u16*)(wsb + A_OFF);
  u16* P = (u16*)(wsb + P_OFF);

  prep_kernel<<<3072, 256, 0, stream>>>(bw, sw, sc, mask, x, Bpack, bias_part, Adense);
  // MEASUREMENT: 5x idempotent gemm replays; gemm_steady = (dur - 136.2)/4.
  gemm_fused<<<512, 512, 0, stream>>>(Adense, Bpack, P);
  gemm_fused<<<512, 512, 0, stream>>>(Adense, Bpack, P);
  gemm_fused<<<512, 512, 0, stream>>>(Adense, Bpack, P);
  gemm_fused<<<512, 512, 0, stream>>>(Adense, Bpack, P);
  gemm_fused<<<512, 512, 0, stream>>>(Adense, Bpack, P);
  reduce_kernel<<<256, 256, 0, stream>>>(P, bias_part, (float*)d_out);
}

// Round 8
// 132.815 us; speedup vs baseline: 2.0058x; 2.0058x over previous
//
#include <hip/hip_runtime.h>
#include <hip/hip_bf16.h>

// SegmentDeactivation: KAN layer folded into one bf16 GEMM.
// K = 512*36 (dense-ified 4-sparse cubic B-spline bases) + 512 (silu(x)·W_base)
//   + 512 (x·masked-slope) = 19456. bias = sum of masked intercepts.
// R18: counted-vmcnt pipelined GEMM (T3-minimal + T4). R17 measured gemm =
//      32.5us (5x replay). Same 256x128/BK64/512thr geometry + MFMA order as
//      R15 (bit-identical numerics), now with DOUBLE-buffered LDS (96KB,
//      1 blk/CU), raw s_barrier, and s_waitcnt vmcnt(6): per epoch issue
//      STAGE(t+1) -> other buf, wait vmcnt(6) (= STAGE(t) landed, STAGE(t+1)
//      still in flight), barrier, 32 MFMA, barrier. No vmcnt(0) in the main
//      loop -> loads fly across the whole compute phase (m218 mechanism).
//      SPLITS 32->16: KPS=1216=19*64 uniform, grid 256 = one co-resident
//      round; P halves to 16.8MB (gemm stores + reduce traffic halve).

typedef unsigned short u16;
typedef unsigned int u32;
typedef unsigned long long u64;
typedef __attribute__((ext_vector_type(8))) short short8;
typedef __attribute__((ext_vector_type(4))) float floatx4;

#define IN_F 512
#define OUT_F 512
#define BATCH 1024
#define K_SPLINE (IN_F * 36)            // 18432
#define K_BASE_OFF K_SPLINE
#define K_LIN_OFF (K_SPLINE + IN_F)
#define K_TOT (K_SPLINE + 2 * IN_F)     // 19456
#define SPLITS 16                       // uniform: 16 x 1216 (= 19*64)
#define KPS 1216
#define NIT 19
#define MN (BATCH * OUT_F)

static __device__ inline u16 f2b(float f) {
  union { float f; u32 u; } v; v.f = f;
  u32 r = v.u + 0x7FFFu + ((v.u >> 16) & 1u);  // round-nearest-even
  return (u16)(r >> 16);
}
static __device__ inline float b2f(u32 lo16) {  // bf16 bits (low 16) -> float
  union { u32 u; float f; } v; v.u = lo16 << 16; return v.f;
}

// ---- prep (fused): blocks 0..1023 = pack_b (one o-half each, per-block mask
//      detect, bias block-reduce); blocks 1024..3071 = dense-A build
//      (bix = blk-1024 = b*2 + half; thread t owns (b, i = i0+t)).
__global__ __launch_bounds__(256) void prep_kernel(
    const float* __restrict__ bw, const float* __restrict__ sw,
    const float* __restrict__ sc, const void* __restrict__ maskp,
    const float* __restrict__ x, u16* __restrict__ B,
    float* __restrict__ bias_part, u16* __restrict__ A) {
  __shared__ __align__(16) u64 lds64[1120 * 4];  // 35840B
  __shared__ int sflag;
  __shared__ float ws4[4];
  int blk = blockIdx.x, t = threadIdx.x;

  if (blk >= 1024) {
    // ---- dense A build
    int bix = blk - 1024;
    int b = bix >> 1;
    int i0 = (bix & 1) << 8;
    int i = i0 + t;
    float xv = x[(size_t)b * IN_F + i];

    // zero own 36-col row (72B = 9 u64), no barrier needed before scatter
    u64* myrow = lds64 + t * 9;
#pragma unroll
    for (int j = 0; j < 9; ++j) myrow[j] = 0;

    int mc = (int)floorf((xv + 1.1875f) * 16.0f);
    float gm = (float)mc * 0.0625f - 1.1875f;
    if (xv < gm) { mc -= 1; gm -= 0.0625f; }
    else if (xv >= gm + 0.0625f) { mc += 1; gm += 0.0625f; }
    if (mc >= 0 && mc <= 37) {
      float t_ = (xv - gm) * 16.0f;
      float t2 = t_ * t_, t3 = t2 * t_;
      float omt = 1.0f - t_;
      u16 r0 = f2b(omt * omt * omt * (1.0f / 6.0f));
      u16 r1 = f2b((3.0f * t3 - 6.0f * t2 + 4.0f) * (1.0f / 6.0f));
      u16 r2 = f2b((-3.0f * t3 + 3.0f * t2 + 3.0f * t_ + 1.0f) * (1.0f / 6.0f));
      float f0 = b2f(r0), f1 = b2f(r1), f2 = b2f(r2);
      u16 bv[4] = {r0, r1, r2, f2b(1.0f - f0 - f1 - f2)};
      u16* lds_u = (u16*)lds64;
#pragma unroll
      for (int j = 0; j < 4; ++j) {
        int c = mc - 3 + j;
        if ((u32)c < 35u) lds_u[t * 36 + c] = bv[j];
      }
    }
    __syncthreads();

    // coalesced dump: 256 rows x 36 u16 = 2304 u64
    u64* dstA = (u64*)(A + (size_t)b * K_TOT + (size_t)i0 * 36);
#pragma unroll
    for (int j = 0; j < 9; ++j) dstA[j * 256 + t] = lds64[j * 256 + t];

    // base / linear columns of A
    float sl = xv / (1.0f + __expf(-xv));
    A[(size_t)b * K_TOT + K_BASE_OFF + i] = f2b(sl);
    A[(size_t)b * K_TOT + K_LIN_OFF + i] = f2b(xv);
    return;
  }

  // ---- pack_b: id = o*512+i, o = blk>>1
  float* lds_f = (float*)lds64;
  int id = blk * 256 + t;
  int o = id >> 9, i = id & 511;
  int i0 = (blk & 1) * 256;

  // stage 35*256 floats = 2240 float4, vectorized (G13)
  const float* swb = sw + ((size_t)o * 512 + i0) * 35;
  const floatx4* sw4 = (const floatx4*)swb;
  floatx4* lds4 = (floatx4*)lds_f;
#pragma unroll
  for (int j = 0; j < 8; ++j) lds4[j * 256 + t] = sw4[j * 256 + t];
  if (t < 192) lds4[8 * 256 + t] = sw4[8 * 256 + t];

  // per-block mask dtype detect over THIS block's entries only.
  const u32* mw = (const u32*)maskp;
  if (t == 0) sflag = 0;
  __syncthreads();
  if (t < 64) {
    u32 w2 = mw[blk * 64 + t];   // uint8 window: bytes [blk*256,+256)
    if ((w2 & 0xFFFFFF00u) && w2 != 0x3F800000u) atomicOr(&sflag, 1);
  }
  __syncthreads();
  int fl = sflag;
  if (!(fl & 1)) {
    u32 w1 = mw[blk * 256 + t];  // int32/f32 window: words [blk*256,+256)
    if (w1 == 0x3F800000u) atomicOr(&sflag, 2);
  }
  __syncthreads();
  fl = sflag;
  bool mk;
  if (fl & 1)      mk = ((const unsigned char*)maskp)[id] != 0;
  else if (fl & 2) mk = ((const float*)maskp)[id] != 0.0f;
  else             mk = ((const int*)maskp)[id] != 0;

  float s = sc[id];
  float w[35];
#pragma unroll
  for (int c = 0; c < 35; ++c) w[c] = lds_f[t * 35 + c] * s;
  __syncthreads();

  // linear fallback params from endpoint spline values (dx = 2 exactly)
  float ys = (w[0] + 4.0f * w[1] + w[2]) * (1.0f / 6.0f);
  float ye = (w[32] + 4.0f * w[33] + w[34]) * (1.0f / 6.0f);
  float a = (ye - ys) * 0.5f;
  float bl = ys + a;

  // build out-row in regs (static indexing), store as 9 u64
  union { u16 r16[36]; u64 r64[9]; } ur;
#pragma unroll
  for (int c = 0; c < 35; ++c) ur.r16[c] = f2b(mk ? 0.0f : w[c]);
  ur.r16[35] = 0;
  u64* myrow = lds64 + t * 9;
#pragma unroll
  for (int j = 0; j < 9; ++j) myrow[j] = ur.r64[j];

  B[(size_t)o * K_TOT + K_BASE_OFF + i] = f2b(bw[id]);
  B[(size_t)o * K_TOT + K_LIN_OFF + i] = f2b(mk ? a : 0.0f);

  // bias block-reduce: sum of (mk ? bl : 0) over this block's 256 i's
  float v = mk ? bl : 0.0f;
#pragma unroll
  for (int off = 32; off >= 1; off >>= 1) v += __shfl_down(v, off);
  if ((t & 63) == 0) ws4[t >> 6] = v;
  __syncthreads();
  if (t == 0) bias_part[blk] = ws4[0] + ws4[1] + ws4[2] + ws4[3];

  u64* dst = (u64*)(B + (size_t)o * K_TOT + (size_t)i0 * 36);
#pragma unroll
  for (int j = 0; j < 9; ++j) dst[j * 256 + t] = lds64[j * 256 + t];
}

// ---- pipelined GEMM: 256x128 tile, BK=64, 512 thr (8 waves 4Mx2N, wave =
// 64x64, acc 4x4, 32 MFMA/epoch). Grid 256 = 1 blk/CU, one co-resident round.
// Double-buffered LDS (96KB). Epoch: STAGE(t+1)->other buf (6 gload_lds w16),
// s_waitcnt vmcnt(6) [STAGE(t) landed, STAGE(t+1) flying], s_barrier,
// 32 MFMA on buf[cur], s_barrier [protect cur from STAGE(t+2)].
__global__ __launch_bounds__(512, 2) void gemm_fused(const u16* __restrict__ A,
                                                     const u16* __restrict__ Bp,
                                                     u16* __restrict__ P) {
  __shared__ u16 As[2][256 * 64];   // 2 x 32 KB
  __shared__ u16 Bs[2][128 * 64];   // 2 x 16 KB

  int t = threadIdx.x;
  int p = blockIdx.x;
  int tile = p & 15, ks = p >> 4;        // 16 tiles x 16 splits
  int bm = tile >> 2, bn = tile & 3;

  int w = t >> 6, l = t & 63;
  int wm = w & 3, wn = w >> 2;           // 4 M-waves x 2 N-waves

  floatx4 acc[4][4];
#pragma unroll
  for (int pp = 0; pp < 4; ++pp)
#pragma unroll
    for (int q = 0; q < 4; ++q) acc[pp][q] = (floatx4)0.0f;

  int k0s = ks * KPS;

  // staging: thread t covers (row ra = t>>3 in each 64-row group, chunk t&7);
  // global source column pre-swizzled so linear LDS dest == swizzled layout.
  int ra = t >> 3;                       // 0..63
  int cg = (t & 7) ^ (ra & 7);
  const u16* Agp = A + (size_t)(bm * 256 + ra) * K_TOT + k0s + cg * 8;
  const u16* Bgp = Bp + (size_t)(bn * 128 + ra) * K_TOT + k0s + cg * 8;

  int mr = l & 15;
  int cq = l >> 4;

  // 6 gload_lds w16 per thread per STAGE (4 A-groups + 2 B-groups)
#define STAGE(buf, koff)                                                       \
  do {                                                                         \
    const u16* a_ = Agp + (koff);                                              \
    const u16* b_ = Bgp + (koff);                                              \
    __builtin_amdgcn_global_load_lds(                                          \
        (const __attribute__((address_space(1))) void*)a_,                     \
        (__attribute__((address_space(3))) void*)(&As[buf][t * 8]), 16, 0, 0); \
    __builtin_amdgcn_global_load_lds(                                          \
        (const __attribute__((address_space(1))) void*)(a_ + (size_t)64 * K_TOT),   \
        (__attribute__((address_space(3))) void*)(&As[buf][4096 + t * 8]), 16, 0, 0);\
    __builtin_amdgcn_global_load_lds(                                          \
        (const __attribute__((address_space(1))) void*)(a_ + (size_t)128 * K_TOT),  \
        (__attribute__((address_space(3))) void*)(&As[buf][8192 + t * 8]), 16, 0, 0);\
    __builtin_amdgcn_global_load_lds(                                          \
        (const __attribute__((address_space(1))) void*)(a_ + (size_t)192 * K_TOT),  \
        (__attribute__((address_space(3))) void*)(&As[buf][12288 + t * 8]), 16, 0, 0);\
    __builtin_amdgcn_global_load_lds(                                          \
        (const __attribute__((address_space(1))) void*)b_,                     \
        (__attribute__((address_space(3))) void*)(&Bs[buf][t * 8]), 16, 0, 0); \
    __builtin_amdgcn_global_load_lds(                                          \
        (const __attribute__((address_space(1))) void*)(b_ + (size_t)64 * K_TOT),   \
        (__attribute__((address_space(3))) void*)(&Bs[buf][4096 + t * 8]), 16, 0, 0);\
  } while (0)

  STAGE(0, 0);   // prologue: tile 0 in flight

  for (int kk = 0; kk < NIT; ++kk) {
    int cur = kk & 1;
    if (kk + 1 < NIT) {
      STAGE(cur ^ 1, (kk + 1) * 64);     // flies across this epoch's MFMA
      asm volatile("s_waitcnt vmcnt(6)" ::: "memory");  // STAGE(kk) landed
    } else {
      asm volatile("s_waitcnt vmcnt(0)" ::: "memory");  // last tile landed
    }
    __builtin_amdgcn_s_barrier();        // all waves' cur-stage complete
    __builtin_amdgcn_sched_barrier(0);

    const u16* Ac = &As[cur][0];
    const u16* Bc = &Bs[cur][0];
#pragma unroll
    for (int h = 0; h < 2; ++h) {
      short8 af[4], bf[4];
      int c = h * 4 + cq;
#pragma unroll
      for (int tm = 0; tm < 4; ++tm) {
        int row = wm * 64 + tm * 16 + mr;
        af[tm] = *(const short8*)&Ac[row * 64 + ((c ^ (row & 7)) << 3)];
      }
#pragma unroll
      for (int tn = 0; tn < 4; ++tn) {
        int row = wn * 64 + tn * 16 + mr;
        bf[tn] = *(const short8*)&Bc[row * 64 + ((c ^ (row & 7)) << 3)];
      }
#pragma unroll
      for (int tm = 0; tm < 4; ++tm)
#pragma unroll
        for (int tn = 0; tn < 4; ++tn)
          acc[tm][tn] = __builtin_amdgcn_mfma_f32_16x16x32_bf16(af[tm], bf[tn], acc[tm][tn], 0, 0, 0);
    }

    __builtin_amdgcn_s_barrier();        // cur reads done before re-stage
    __builtin_amdgcn_sched_barrier(0);
  }
#undef STAGE

  // ---- epilogue: direct coalesced bf16 partial store, fixed per-thread layout.
  // per (tile, ks): 256x128 = 32768 u16; chunk q (0..7) x 512 thr x 8 u16.
  u16* Pb = P + ((size_t)tile * SPLITS + ks) * 32768;
#pragma unroll
  for (int q = 0; q < 8; ++q) {
    int tm = q >> 1, tn0 = (q & 1) * 2;
    u16 r[8];
#pragma unroll
    for (int z = 0; z < 4; ++z) r[z] = f2b(acc[tm][tn0][z]);
#pragma unroll
    for (int z = 0; z < 4; ++z) r[4 + z] = f2b(acc[tm][tn0 + 1][z]);
    *(short8*)(Pb + q * 4096 + t * 8) = *(short8*)r;
  }
}

// ---- reduce 16 bf16 partial tiles + bias -> fp32 out (decodes C-layout)
__global__ __launch_bounds__(256) void reduce_kernel(const u16* __restrict__ P,
                                                     const float* __restrict__ bias_part,
                                                     float* __restrict__ out) {
  int rid = blockIdx.x * 256 + threadIdx.x;  // 65536 = tile*4096 + q*512 + t
  int tile = rid >> 12;                      // 0..15
  int rem = rid & 4095;
  int q = rem >> 9, t = rem & 511;
  const u16* base = P + (size_t)tile * SPLITS * 32768 + q * 4096 + t * 8;

  float s[8] = {0, 0, 0, 0, 0, 0, 0, 0};
#pragma unroll
  for (int ks = 0; ks < SPLITS; ++ks) {
    short8 v = *(const short8*)(base + (size_t)ks * 32768);
#pragma unroll
    for (int j = 0; j < 8; ++j) s[j] += b2f((u32)(u16)v[j]);
  }

  int w = t >> 6, l = t & 63;
  int wm = w & 3, wn = w >> 2;
  int bm = tile >> 2, bn = tile & 3;
  int row0 = bm * 256 + wm * 64 + ((l >> 4) << 2);
  int col0 = bn * 128 + wn * 64 + (l & 15);
  int tm = q >> 1, tn0 = (q & 1) * 2;
#pragma unroll
  for (int j = 0; j < 8; ++j) {
    int tn = tn0 + (j >> 2), rr = j & 3;
    int row = row0 + tm * 16 + rr;
    int col = col0 + tn * 16;
    float bsv = bias_part[2 * col] + bias_part[2 * col + 1];
    out[(size_t)row * OUT_F + col] = s[j] + bsv;
  }
}

extern "C" void kernel_launch(void* const* d_in, const int* in_sizes, int n_in,
                              void* d_out, int out_size, void* d_ws, size_t ws_size,
                              hipStream_t stream) {
  const float* x  = (const float*)d_in[0];
  const float* bw = (const float*)d_in[1];
  const float* sw = (const float*)d_in[2];
  const float* sc = (const float*)d_in[3];
  // d_in[4] = grid: uniform h=1/16 extended knots, constants baked in.
  const void* mask = d_in[5];

  const size_t B_BYTES = (size_t)OUT_F * K_TOT * 2;         // 19,922,944
  const size_t BIAS_OFF = B_BYTES;                          // 1024 floats
  const size_t A_OFF = B_BYTES + 8192;
  const size_t A_BYTES = (size_t)BATCH * K_TOT * 2;         // 39,845,888
  const size_t P_OFF = A_OFF + A_BYTES;                     // P: 16,777,216

  char* wsb = (char*)d_ws;
  u16* Bpack = (u16*)wsb;
  float* bias_part = (float*)(wsb + BIAS_OFF);
  u16* Adense = (u16*)(wsb + A_OFF);
  u16* P = (u16*)(wsb + P_OFF);

  prep_kernel<<<3072, 256, 0, stream>>>(bw, sw, sc, mask, x, Bpack, bias_part, Adense);
  gemm_fused<<<256, 512, 0, stream>>>(Adense, Bpack, P);
  reduce_kernel<<<256, 256, 0, stream>>>(P, bias_part, (float*)d_out);
}